// Round 7
// baseline (171.965 us; speedup 1.0000x reference)
//
#include <hip/hip_runtime.h>

#define VOCAB 1024
#define HIDDEN 64
#define N_POS 131072            // 32*64*64 positions
#define Q_ELEMS 8388608
#define BPOS 512                // positions per block
#define NBLK 256                // 1 block per CU

// d_out layout (floats): [0]=loss, [1..8388608]=quantized_st (NCHW),
// [8388609]=perplexity, [8388610..]=one_hot [131072,1024]
#define OUT_Q_OFF 1
#define OUT_PPL_OFF 8388609
#define OUT_OH_OFF 8388610ULL

typedef __attribute__((ext_vector_type(8))) short short8v;  // bf16x8 MFMA frag
typedef __attribute__((ext_vector_type(4))) float f32x4;

__device__ __forceinline__ short bf16r(float f) {
    union { float f; unsigned u; } v; v.f = f;
    unsigned r = v.u + 0x7FFFu + ((v.u >> 16) & 1u);   // RNE
    return (short)(r >> 16);
}

// one float4 slot s covers flat floats [4s+2, 4s+6) of the block's one_hot
// slice; generate zeros with the data-dependent 1.0 folded in.
__device__ __forceinline__ void oh_slot(f32x4* oh4, const int* idx_lds, int s) {
    const int f0 = 4 * s + 2;
    const int r  = f0 >> 10;
    const int j0 = f0 & 1023;
    const int ja = idx_lds[r];
    const int rb = (j0 == 1022) ? r + 1 : r;   // slot straddles rows r, r+1
    const int jb = idx_lds[rb];
    f32x4 v;
    v[0] = (ja == j0)                ? 1.f : 0.f;
    v[1] = (ja == j0 + 1)            ? 1.f : 0.f;
    v[2] = (jb == ((j0 + 2) & 1023)) ? 1.f : 0.f;
    v[3] = (jb == ((j0 + 3) & 1023)) ? 1.f : 0.f;
    __builtin_nontemporal_store(v, &oh4[s]);
}

// 512 threads: waves 0-3 compute, waves 4-7 write. Pipeline:
//  stage(all) -> B1 -> t0 argmax -> B2 -> {writers: t0 one_hot stream}
//  || {compute: t1 argmax} -> B3 -> {writers: t1 stream} || {compute: q +
//  hist + loss + its own one_hot share}. All 8 waves store in the last phase.
__global__ __launch_bounds__(512, 1) void vq_main(
    const float* __restrict__ in, const float* __restrict__ cb,
    float* __restrict__ out, float* __restrict__ ws_loss,
    unsigned* __restrict__ counts)
{
    __shared__ short cbs[VOCAB * HIDDEN];   // 128 KB, XOR-swizzled bf16
    __shared__ float bsqs[VOCAB];           // -0.5*|c|^2
    __shared__ unsigned hist[VOCAB];
    __shared__ int   idx_lds[BPOS];

    const int tid  = threadIdx.x;
    const int base = blockIdx.x * BPOS;
    const int b    = base >> 12;            // NCHW batch index, uniform
    const int hw0  = base & 4095;
    float* ohflat = out + OUT_OH_OFF + (size_t)base * VOCAB;   // 524288 floats
    f32x4* oh4    = (f32x4*)(ohflat + 2);                      // 16B aligned

    for (int k = tid; k < VOCAB; k += 512) hist[k] = 0u;

    // ---- stage ALL 1024 codes as swizzled bf16 (all 8 waves) ----
    {
        const float4* src = (const float4*)cb;
#pragma unroll 4
        for (int it = 0; it < 32; ++it) {
            int i = tid + it * 512;
            int row = i >> 4, c4 = i & 15;
            float4 v = src[i];
            float ss = v.x * v.x + v.y * v.y + v.z * v.z + v.w * v.w;
            ss += __shfl_xor(ss, 1);
            ss += __shfl_xor(ss, 2);
            ss += __shfl_xor(ss, 4);
            ss += __shfl_xor(ss, 8);
            unsigned lo = ((unsigned)(unsigned short)bf16r(v.x))
                        | ((unsigned)(unsigned short)bf16r(v.y) << 16);
            unsigned hi = ((unsigned)(unsigned short)bf16r(v.z))
                        | ((unsigned)(unsigned short)bf16r(v.w) << 16);
            int boff = row * 128 + ((c4 * 8) ^ ((row & 7) << 4));
            *(uint2*)((char*)cbs + boff) = make_uint2(lo, hi);
            if (c4 == 0) bsqs[row] = -0.5f * ss;
        }
    }

    if (tid < 256) {
        // ======================= compute waves =======================
        const int wid = tid >> 6, lane = tid & 63;
        const int l15 = lane & 15, kg = lane >> 4;
        const int kg4 = kg << 2, kgb = kg << 4;

        // x fragments + |x|^2 for both tiles (overlaps staging loads)
        short8v xf[2][4][2];
        float xsq[2][4];
#pragma unroll
        for (int t = 0; t < 2; ++t)
#pragma unroll
        for (int bt = 0; bt < 4; ++bt) {
            xsq[t][bt] = 0.f;
#pragma unroll
            for (int kh = 0; kh < 2; ++kh) {
                const float* xp = in + (size_t)b * 262144
                                + (size_t)(kh * 32 + kg * 8) * 4096
                                + hw0 + t * 256 + wid * 64 + bt * 16 + l15;
                short8v v;
#pragma unroll
                for (int e = 0; e < 8; ++e) {
                    float x = xp[(size_t)e * 4096];
                    xsq[t][bt] = fmaf(x, x, xsq[t][bt]);
                    v[e] = bf16r(x);
                }
                xf[t][bt][kh] = v;
            }
        }

        asm volatile("s_waitcnt vmcnt(0) lgkmcnt(0)" ::: "memory");
        __builtin_amdgcn_sched_barrier(0);
        __builtin_amdgcn_s_barrier();                      // B1: staging done
        __builtin_amdgcn_sched_barrier(0);

        float lsum = 0.f;
#pragma unroll
        for (int t = 0; t < 2; ++t) {
            float rm[4];
#pragma unroll
            for (int bt = 0; bt < 4; ++bt) rm[bt] = -3.4e38f;

            for (int ct = 0; ct < 64; ++ct) {
                const int rbase = ct * 16 + l15;           // A-frag row = code
                const char* arow = (const char*)cbs + rbase * 128;
                const int sw = (rbase & 7) << 4;
                short8v a0 = *(const short8v*)(arow + (kgb ^ sw));
                short8v a1 = *(const short8v*)(arow + ((64 + kgb) ^ sw));
                f32x4 bsq4 = *(const f32x4*)&bsqs[ct * 16 + kg4];
                const unsigned jb = (unsigned)(ct * 16 + kg4);
#pragma unroll
                for (int bt = 0; bt < 4; ++bt) {
                    f32x4 acc = bsq4;
                    acc = __builtin_amdgcn_mfma_f32_16x16x32_bf16(a0, xf[t][bt][0], acc, 0, 0, 0);
                    acc = __builtin_amdgcn_mfma_f32_16x16x32_bf16(a1, xf[t][bt][1], acc, 0, 0, 0);
#pragma unroll
                    for (int r = 0; r < 4; ++r) {
                        unsigned pj = (__float_as_uint(acc[r]) & 0xFFFFFC00u) | (jb + r);
                        rm[bt] = fmaxf(rm[bt], __uint_as_float(pj));
                    }
                }
            }
#pragma unroll
            for (int bt = 0; bt < 4; ++bt) {
                float m  = rm[bt];
                float xs = xsq[t][bt];
                m  = fmaxf(m, __shfl_xor(m, 16));
                xs += __shfl_xor(xs, 16);
                m  = fmaxf(m, __shfl_xor(m, 32));
                xs += __shfl_xor(xs, 32);
                if (kg == 0) {
                    unsigned mu = __float_as_uint(m);
                    int j = (int)(mu & 1023u);
                    float mval = __uint_as_float(mu & 0xFFFFFC00u);
                    idx_lds[t * 256 + wid * 64 + bt * 16 + l15] = j;
                    atomicAdd(&hist[j], 1u);
                    lsum += xs - 2.f * mval;   // |x-c|^2 = |x|^2 - 2(x.c - .5|c|^2)
                }
            }
            asm volatile("s_waitcnt lgkmcnt(0)" ::: "memory");
            __builtin_amdgcn_sched_barrier(0);
            __builtin_amdgcn_s_barrier();                  // B2 (t=0) / B3 (t=1)
            __builtin_amdgcn_sched_barrier(0);
        }

        // ---- q writes (fp32 gather), hist flush, loss ----
#pragma unroll
        for (int t = 0; t < 2; ++t) {
            const int jf = idx_lds[t * 256 + tid];
            const float* cr = cb + (size_t)jf * HIDDEN;
            float* qp = out + OUT_Q_OFF + (size_t)b * 262144 + hw0 + t * 256 + tid;
#pragma unroll
            for (int c = 0; c < HIDDEN; ++c)
                __builtin_nontemporal_store(cr[c], &qp[(size_t)c * 4096]);
        }
        for (int k = tid; k < VOCAB; k += 256) {
            unsigned h = hist[k];
            if (h) atomicAdd(&counts[k], h);
        }
#pragma unroll
        for (int off = 32; off; off >>= 1) lsum += __shfl_down(lsum, off);
        if (lane == 0) atomicAdd(ws_loss, lsum);

        // ---- compute waves' one_hot share: slots [114687, 131071) ----
#pragma unroll 2
        for (int it = 0; it < 64; ++it)
            oh_slot(oh4, idx_lds, 114687 + tid + it * 256);
        if (tid == 0) {        // tail floats 524286..7 = row 511, cols 1022..3
            const int ja = idx_lds[511];
            *(float2*)(ohflat + 524286) = make_float2(ja == 1022 ? 1.f : 0.f,
                                                      ja == 1023 ? 1.f : 0.f);
        }
    } else {
        // ======================= writer waves =======================
        const int w = tid - 256;                 // 0..255
        asm volatile("s_waitcnt vmcnt(0) lgkmcnt(0)" ::: "memory");
        __builtin_amdgcn_sched_barrier(0);
        __builtin_amdgcn_s_barrier();                      // B1
        __builtin_amdgcn_sched_barrier(0);

        __builtin_amdgcn_s_barrier();                      // B2: tile-0 idx ready
        __builtin_amdgcn_sched_barrier(0);
        // tile-0 stream: slots [0, 65535) touch only rows 0..255
        for (int s = w; s < 65535; s += 256) oh_slot(oh4, idx_lds, s);
        if (w == 0) {          // head floats 0..1 = row 0, cols 0..1
            const int ja = idx_lds[0];
            *(float2*)ohflat = make_float2(ja == 0 ? 1.f : 0.f,
                                           ja == 1 ? 1.f : 0.f);
        }

        __builtin_amdgcn_s_barrier();                      // B3: tile-1 idx ready
        __builtin_amdgcn_sched_barrier(0);
        // tile-1 writer share: slots [65535, 114687)
        for (int s = 65535 + w; s < 114687; s += 256) oh_slot(oh4, idx_lds, s);
    }
}

__global__ void vq_finalize(const unsigned* __restrict__ counts,
                            const float* __restrict__ ws_loss,
                            float* __restrict__ out)
{
    __shared__ double red[4];
    const int tid = threadIdx.x;
    double s = 0.0;
    for (int k = tid; k < VOCAB; k += 256) {
        double p = (double)counts[k] / (double)N_POS;
        s += -p * log(p + 1e-10);
    }
#pragma unroll
    for (int off = 32; off; off >>= 1) s += __shfl_down(s, off);
    if ((tid & 63) == 0) red[tid >> 6] = s;
    __syncthreads();
    if (tid == 0) {
        double e = red[0] + red[1] + red[2] + red[3];
        out[OUT_PPL_OFF] = (float)exp(e);
        out[0] = ws_loss[0] * 1.25f / (float)Q_ELEMS;
    }
}

extern "C" void kernel_launch(void* const* d_in, const int* in_sizes, int n_in,
                              void* d_out, int out_size, void* d_ws, size_t ws_size,
                              hipStream_t stream) {
    const float* in = (const float*)d_in[0];
    const float* cb = (const float*)d_in[1];
    float* out = (float*)d_out;

    float*    ws_loss = (float*)d_ws;                 // 4 B
    unsigned* counts  = (unsigned*)d_ws + 64;         // bytes 256..4352

    hipMemsetAsync(d_ws, 0, 4352, stream);            // zero loss accum + counts
    vq_main<<<NBLK, 512, 0, stream>>>(in, cb, out, ws_loss, counts);
    vq_finalize<<<1, 256, 0, stream>>>(counts, ws_loss, out);
}